// Round 1
// baseline (209.436 us; speedup 1.0000x reference)
//
#include <hip/hip_runtime.h>

#ifndef __has_builtin
#define __has_builtin(x) 0
#endif
#if __has_builtin(__builtin_amdgcn_exp2f)
#define EXP2F(x) __builtin_amdgcn_exp2f(x)
#else
#define EXP2F(x) exp2f(x)
#endif

namespace {

constexpr int T = 4096;
constexpr int C = 128;
constexpr int H = 8;
constexpr int D = 16;
constexpr int BH = 16;                         // B*H
constexpr size_t PLANE = (size_t)BH * T * D;   // 1,048,576 floats per tensor

// ---------------------------------------------------------------------------
// Kernel 1: QKV projection.  Ccat[t][c] = sum_k x[t][k] * Wcat[c][k]
// (torch Linear => x @ W.T).  Output scattered into qkv[mat][b*H+h][t][d].
// M=8192, N=384 (3 mats x 128), K=128.  64x64 tiles, 256 thr, 4x4/thread.
// ---------------------------------------------------------------------------
__global__ __launch_bounds__(256) void qkv_proj(
    const float* __restrict__ x, const float* __restrict__ Wq,
    const float* __restrict__ Wk, const float* __restrict__ Wv,
    float* __restrict__ qkv) {
  __shared__ float Xs[128][68];  // [k][m]; stride 68 => 16B-aligned b128 reads, banks spread
  __shared__ float Ws[128][68];  // [k][n]
  const int tid = threadIdx.x;
  const int bm = blockIdx.x;            // 128 row blocks
  const int bn = blockIdx.y;            // 6 col blocks
  const int mat = bn >> 1;              // 0=Q 1=K 2=V
  const int c0 = (bn & 1) * 64;         // col offset within the matrix
  const float* W = (mat == 0) ? Wq : (mat == 1) ? Wk : Wv;
  const int t0 = bm * 64;

  const float4* xsrc = (const float4*)(x + (size_t)t0 * C);
  const float4* wsrc = (const float4*)(W + (size_t)c0 * C);
  for (int f = tid; f < 2048; f += 256) {
    const int m = f >> 5, k = (f & 31) << 2;
    float4 v = xsrc[f];
    Xs[k + 0][m] = v.x; Xs[k + 1][m] = v.y; Xs[k + 2][m] = v.z; Xs[k + 3][m] = v.w;
    float4 u = wsrc[f];
    Ws[k + 0][m] = u.x; Ws[k + 1][m] = u.y; Ws[k + 2][m] = u.z; Ws[k + 3][m] = u.w;
  }
  __syncthreads();

  const int tx = tid & 15, ty = tid >> 4;
  float acc[4][4] = {};
#pragma unroll 8
  for (int k = 0; k < 128; ++k) {
    const float4 a = *(const float4*)&Xs[k][ty * 4];
    const float4 b = *(const float4*)&Ws[k][tx * 4];
    const float av[4] = {a.x, a.y, a.z, a.w};
    const float bv[4] = {b.x, b.y, b.z, b.w};
#pragma unroll
    for (int i = 0; i < 4; ++i)
#pragma unroll
      for (int j = 0; j < 4; ++j) acc[i][j] = fmaf(av[i], bv[j], acc[i][j]);
  }

  const int cm = c0 + tx * 4;          // column within this matrix, 4-aligned
  const int h = cm >> 4, d0 = cm & 15; // 4 consecutive d stay inside one head
#pragma unroll
  for (int i = 0; i < 4; ++i) {
    const int tr = t0 + ty * 4 + i;
    const int b = tr >> 12, t = tr & (T - 1);
    const float4 v = make_float4(acc[i][0], acc[i][1], acc[i][2], acc[i][3]);
    *(float4*)(qkv + (((size_t)mat * BH + b * H + h) * T + t) * D + d0) = v;
  }
}

// ---------------------------------------------------------------------------
// Kernel 2: causal flash attention, fp32 vector ALU.
// Grid: 1024 blocks = (qb in [0,64)) x (bh in [0,16)), 256 threads = 4 waves.
// Wave w handles key-blocks w, w+4, ... (split-K); partials merged via LDS.
// Each lane owns one query row; K/V tiles staged into per-wave LDS regions.
// ---------------------------------------------------------------------------
__global__ __launch_bounds__(256) void attn_fwd(
    const float* __restrict__ qkv, float* __restrict__ att) {
  __shared__ float kvs[4][2][64][16];  // [wave][K/V][key][d]  32 KiB
  __shared__ float red[4][64][18];     // m, l, o[16]          18 KiB
  const int tid = threadIdx.x;
  const int w = tid >> 6, lane = tid & 63;
  const int g = blockIdx.x;
  const int qb = 63 - (g >> 4);        // big blocks dispatch first (load balance)
  const int bh = g & 15;
  const float* Qp = qkv;
  const float* Kp = qkv + PLANE;
  const float* Vp = qkv + 2 * PLANE;
  const int trow = qb * 64 + lane;

  // q row, pre-scaled by D^-1/2 * log2(e) so softmax uses exp2
  float qs[16];
  {
    const float4* qrow = (const float4*)(Qp + ((size_t)bh * T + trow) * D);
    const float sc = 0.25f * 1.4426950408889634f;
#pragma unroll
    for (int i = 0; i < 4; ++i) {
      const float4 v = qrow[i];
      qs[i * 4 + 0] = v.x * sc; qs[i * 4 + 1] = v.y * sc;
      qs[i * 4 + 2] = v.z * sc; qs[i * 4 + 3] = v.w * sc;
    }
  }

  float m = -1e30f, l = 0.f;
  float o[16];
#pragma unroll
  for (int d = 0; d < 16; ++d) o[d] = 0.f;

  float* kbuf = &kvs[w][0][0][0];
  float* vbuf = &kvs[w][1][0][0];
  const float4* kb4 = (const float4*)kbuf;
  const float4* vb4 = (const float4*)vbuf;

  auto process = [&](int kb, bool diag) {
    // stage this wave's K/V tile (private region -> no cross-wave barrier)
    const float4* ksrc = (const float4*)(Kp + ((size_t)bh * T + kb * 64) * D);
    const float4* vsrc = (const float4*)(Vp + ((size_t)bh * T + kb * 64) * D);
    float4* kdst = (float4*)kbuf;
    float4* vdst = (float4*)vbuf;
#pragma unroll
    for (int i = 0; i < 4; ++i) {
      kdst[lane + 64 * i] = ksrc[lane + 64 * i];
      vdst[lane + 64 * i] = vsrc[lane + 64 * i];
    }
    asm volatile("s_waitcnt vmcnt(0) lgkmcnt(0)" ::: "memory");

#pragma unroll 1
    for (int ch = 0; ch < 4; ++ch) {   // 16-key chunks keep regs + I-cache small
      float s[16];
#pragma unroll
      for (int j = 0; j < 16; ++j) {
        const int kj = ch * 64 + j * 4;
        const float4 k0 = kb4[kj + 0];
        const float4 k1 = kb4[kj + 1];
        const float4 k2 = kb4[kj + 2];
        const float4 k3 = kb4[kj + 3];
        float a0 = fmaf(qs[1], k0.y, qs[0] * k0.x);
        a0 = fmaf(qs[2], k0.z, a0); a0 = fmaf(qs[3], k0.w, a0);
        float a1 = fmaf(qs[5], k1.y, qs[4] * k1.x);
        a1 = fmaf(qs[6], k1.z, a1); a1 = fmaf(qs[7], k1.w, a1);
        float a2 = fmaf(qs[9], k2.y, qs[8] * k2.x);
        a2 = fmaf(qs[10], k2.z, a2); a2 = fmaf(qs[11], k2.w, a2);
        float a3 = fmaf(qs[13], k3.y, qs[12] * k3.x);
        a3 = fmaf(qs[14], k3.z, a3); a3 = fmaf(qs[15], k3.w, a3);
        s[j] = (a0 + a1) + (a2 + a3);
      }
      if (diag) {
        const int j0 = ch * 16;
#pragma unroll
        for (int j = 0; j < 16; ++j)
          if (j0 + j > lane) s[j] = -1e30f;   // key index > query row
      }
      float bm = s[0];
#pragma unroll
      for (int j = 1; j < 16; ++j) bm = fmaxf(bm, s[j]);
      const float mn = fmaxf(m, bm);
      const float alpha = EXP2F(m - mn);
      m = mn;
      l *= alpha;
#pragma unroll
      for (int d = 0; d < 16; ++d) o[d] *= alpha;
#pragma unroll
      for (int j = 0; j < 16; ++j) {
        const float p = EXP2F(s[j] - mn);
        l += p;
        const int vj = ch * 64 + j * 4;
        const float4 v0 = vb4[vj + 0];
        const float4 v1 = vb4[vj + 1];
        const float4 v2 = vb4[vj + 2];
        const float4 v3 = vb4[vj + 3];
        o[0] = fmaf(p, v0.x, o[0]);  o[1] = fmaf(p, v0.y, o[1]);
        o[2] = fmaf(p, v0.z, o[2]);  o[3] = fmaf(p, v0.w, o[3]);
        o[4] = fmaf(p, v1.x, o[4]);  o[5] = fmaf(p, v1.y, o[5]);
        o[6] = fmaf(p, v1.z, o[6]);  o[7] = fmaf(p, v1.w, o[7]);
        o[8] = fmaf(p, v2.x, o[8]);  o[9] = fmaf(p, v2.y, o[9]);
        o[10] = fmaf(p, v2.z, o[10]); o[11] = fmaf(p, v2.w, o[11]);
        o[12] = fmaf(p, v3.x, o[12]); o[13] = fmaf(p, v3.y, o[13]);
        o[14] = fmaf(p, v3.z, o[14]); o[15] = fmaf(p, v3.w, o[15]);
      }
    }
  };

  for (int kb = w; kb < qb; kb += 4) process(kb, false);
  if ((qb & 3) == w) process(qb, true);  // diagonal (masked) block

  // merge the 4 waves' partials
  red[w][lane][0] = m;
  red[w][lane][1] = l;
#pragma unroll
  for (int d = 0; d < 16; ++d) red[w][lane][2 + d] = o[d];
  __syncthreads();
  if (w == 0) {
    float M = red[0][lane][0];
#pragma unroll
    for (int p = 1; p < 4; ++p) M = fmaxf(M, red[p][lane][0]);
    float L = 0.f, O[16];
#pragma unroll
    for (int d = 0; d < 16; ++d) O[d] = 0.f;
#pragma unroll
    for (int p = 0; p < 4; ++p) {
      const float scp = EXP2F(red[p][lane][0] - M);
      L = fmaf(red[p][lane][1], scp, L);
#pragma unroll
      for (int d = 0; d < 16; ++d) O[d] = fmaf(red[p][lane][2 + d], scp, O[d]);
    }
    const float inv = 1.f / L;
    float4* dst = (float4*)(att + ((size_t)bh * T + trow) * D);
#pragma unroll
    for (int i = 0; i < 4; ++i)
      dst[i] = make_float4(O[i * 4 + 0] * inv, O[i * 4 + 1] * inv,
                           O[i * 4 + 2] * inv, O[i * 4 + 3] * inv);
  }
}

// ---------------------------------------------------------------------------
// Kernel 3: output projection + bias.  out[t][c] = sum_k attflat[t][k]*Wp[c][k] + bp[c]
// attflat[t][h*16+d] = att[bh][t][d].  M=8192, N=128, K=128.
// ---------------------------------------------------------------------------
__global__ __launch_bounds__(256) void out_proj(
    const float* __restrict__ att, const float* __restrict__ Wp,
    const float* __restrict__ bp, float* __restrict__ out) {
  __shared__ float As[128][68];  // [k=c'][m]
  __shared__ float Bs[128][68];  // [k][n]
  const int tid = threadIdx.x;
  const int t0 = blockIdx.x * 64;
  const int c0 = blockIdx.y * 64;

  for (int f = tid; f < 2048; f += 256) {
    const int mm = f & 63;
    const int cp = (f >> 6) << 2;  // feature (c') base, 4-aligned within a head
    const int tr = t0 + mm;
    const int b = tr >> 12, t = tr & (T - 1);
    const int h = cp >> 4, d0 = cp & 15;
    const float4 v = *(const float4*)(att + (((size_t)b * H + h) * T + t) * D + d0);
    As[cp + 0][mm] = v.x; As[cp + 1][mm] = v.y; As[cp + 2][mm] = v.z; As[cp + 3][mm] = v.w;
  }
  const float4* wsrc = (const float4*)(Wp + (size_t)c0 * C);
  for (int f = tid; f < 2048; f += 256) {
    const float4 v = wsrc[f];
    const int n = f >> 5, k = (f & 31) << 2;
    Bs[k + 0][n] = v.x; Bs[k + 1][n] = v.y; Bs[k + 2][n] = v.z; Bs[k + 3][n] = v.w;
  }
  __syncthreads();

  const int tx = tid & 15, ty = tid >> 4;
  float acc[4][4] = {};
#pragma unroll 8
  for (int k = 0; k < 128; ++k) {
    const float4 a = *(const float4*)&As[k][ty * 4];
    const float4 b = *(const float4*)&Bs[k][tx * 4];
    const float av[4] = {a.x, a.y, a.z, a.w};
    const float bv[4] = {b.x, b.y, b.z, b.w};
#pragma unroll
    for (int i = 0; i < 4; ++i)
#pragma unroll
      for (int j = 0; j < 4; ++j) acc[i][j] = fmaf(av[i], bv[j], acc[i][j]);
  }

  const float4 bias = *(const float4*)(bp + c0 + tx * 4);
#pragma unroll
  for (int i = 0; i < 4; ++i) {
    const int tr = t0 + ty * 4 + i;
    const float4 v = make_float4(acc[i][0] + bias.x, acc[i][1] + bias.y,
                                 acc[i][2] + bias.z, acc[i][3] + bias.w);
    *(float4*)(out + (size_t)tr * C + c0 + tx * 4) = v;
  }
}

}  // namespace

extern "C" void kernel_launch(void* const* d_in, const int* in_sizes, int n_in,
                              void* d_out, int out_size, void* d_ws, size_t ws_size,
                              hipStream_t stream) {
  // setup_inputs order: x, Wk, Wq, Wv, Wp, bp
  const float* x  = (const float*)d_in[0];
  const float* Wk = (const float*)d_in[1];
  const float* Wq = (const float*)d_in[2];
  const float* Wv = (const float*)d_in[3];
  const float* Wp = (const float*)d_in[4];
  const float* bp = (const float*)d_in[5];

  float* qkv = (float*)d_ws;           // Q,K,V planes: 3 * 4 MiB
  float* att = qkv + 3 * PLANE;        // attention output: 4 MiB  (needs 16 MiB ws)

  qkv_proj<<<dim3(128, 6), 256, 0, stream>>>(x, Wq, Wk, Wv, qkv);
  attn_fwd<<<dim3(1024), 256, 0, stream>>>(qkv, att);
  out_proj<<<dim3(128, 2), 256, 0, stream>>>(att, Wp, bp, (float*)d_out);
}

// Round 2
// 131.218 us; speedup vs baseline: 1.5961x; 1.5961x over previous
//
#include <hip/hip_runtime.h>

#ifndef __has_builtin
#define __has_builtin(x) 0
#endif
#if __has_builtin(__builtin_amdgcn_exp2f)
#define EXP2F(x) __builtin_amdgcn_exp2f(x)
#else
#define EXP2F(x) exp2f(x)
#endif

namespace {

constexpr int T = 4096;
constexpr int C = 128;
constexpr int H = 8;
constexpr int D = 16;
constexpr int BH = 16;                         // B*H
constexpr size_t PLANE = (size_t)BH * T * D;   // 1,048,576 elements per tensor

using bf16x8 = __attribute__((ext_vector_type(8))) short;
using u16x4  = __attribute__((ext_vector_type(4))) unsigned short;
using f32x4  = __attribute__((ext_vector_type(4))) float;

__device__ __forceinline__ uint32_t cvt_pk_bf16(float lo, float hi) {
  uint32_t r;
  asm volatile("v_cvt_pk_bf16_f32 %0, %1, %2" : "=v"(r) : "v"(lo), "v"(hi));
  return r;
}

// ---------------------------------------------------------------------------
// Kernel 1: QKV projection -> bf16 outputs.
//   Qbf[bh][t][d]  (pre-scaled by D^-1/2 * log2(e))
//   Kbf[bh][t][d]
//   Vt [bh][d][t]  (transposed for the PV MFMA A-operand)
// M=8192, N=384, K=128.  64x64 tiles, 256 thr, 4x4/thread.
// ---------------------------------------------------------------------------
__global__ __launch_bounds__(256) void qkv_proj(
    const float* __restrict__ x, const float* __restrict__ Wq,
    const float* __restrict__ Wk, const float* __restrict__ Wv,
    unsigned short* __restrict__ Qbf, unsigned short* __restrict__ Kbf,
    unsigned short* __restrict__ Vt) {
  __shared__ float Xs[128][68];  // [k][m]
  __shared__ float Ws[128][68];  // [k][n]
  const int tid = threadIdx.x;
  const int bm = blockIdx.x;            // 128 row blocks
  const int bn = blockIdx.y;            // 6 col blocks
  const int mat = bn >> 1;              // 0=Q 1=K 2=V
  const int c0 = (bn & 1) * 64;
  const float* W = (mat == 0) ? Wq : (mat == 1) ? Wk : Wv;
  const int t0 = bm * 64;

  const float4* xsrc = (const float4*)(x + (size_t)t0 * C);
  const float4* wsrc = (const float4*)(W + (size_t)c0 * C);
  for (int f = tid; f < 2048; f += 256) {
    const int m = f >> 5, k = (f & 31) << 2;
    float4 v = xsrc[f];
    Xs[k + 0][m] = v.x; Xs[k + 1][m] = v.y; Xs[k + 2][m] = v.z; Xs[k + 3][m] = v.w;
    float4 u = wsrc[f];
    Ws[k + 0][m] = u.x; Ws[k + 1][m] = u.y; Ws[k + 2][m] = u.z; Ws[k + 3][m] = u.w;
  }
  __syncthreads();

  const int tx = tid & 15, ty = tid >> 4;
  float acc[4][4] = {};
#pragma unroll 8
  for (int k = 0; k < 128; ++k) {
    const float4 a = *(const float4*)&Xs[k][ty * 4];
    const float4 b = *(const float4*)&Ws[k][tx * 4];
    const float av[4] = {a.x, a.y, a.z, a.w};
    const float bv[4] = {b.x, b.y, b.z, b.w};
#pragma unroll
    for (int i = 0; i < 4; ++i)
#pragma unroll
      for (int j = 0; j < 4; ++j) acc[i][j] = fmaf(av[i], bv[j], acc[i][j]);
  }

  const int cm = c0 + tx * 4;          // column within the matrix, 4-aligned
  const int h = cm >> 4, d0 = cm & 15; // 4 consecutive d inside one head
  if (mat < 2) {
    const float sc = (mat == 0) ? 0.25f * 1.4426950408889634f : 1.0f;
    unsigned short* dst = (mat == 0) ? Qbf : Kbf;
#pragma unroll
    for (int i = 0; i < 4; ++i) {
      const int tr = t0 + ty * 4 + i;
      const int b = tr >> 12, t = tr & (T - 1);
      const uint32_t u0 = cvt_pk_bf16(acc[i][0] * sc, acc[i][1] * sc);
      const uint32_t u1 = cvt_pk_bf16(acc[i][2] * sc, acc[i][3] * sc);
      *(uint2*)(dst + (((size_t)(b * H + h)) * T + t) * D + d0) = make_uint2(u0, u1);
    }
  } else {
    // V transposed: Vt[bh][d][t], thread holds 4 consecutive t at 4 consecutive d
    const int tr0 = t0 + ty * 4;
    const int b = tr0 >> 12, t = tr0 & (T - 1);
#pragma unroll
    for (int j = 0; j < 4; ++j) {
      const uint32_t u0 = cvt_pk_bf16(acc[0][j], acc[1][j]);
      const uint32_t u1 = cvt_pk_bf16(acc[2][j], acc[3][j]);
      *(uint2*)(Vt + (((size_t)(b * H + h)) * D + d0 + j) * T + t) = make_uint2(u0, u1);
    }
  }
}

// ---------------------------------------------------------------------------
// Kernel 2: causal flash attention via bf16 MFMA (16x16x32).
// One wave owns one 16-query tile.  Per 32-key step:
//   S^T = mfma(A=K-tile, B=Q^T)   x2 (16 keys each, k-dim zero-padded 16->32)
//   lane l holds S^T[key=k0(+16)+4g+r][q=l&15], g=l>>4   (verified C/D layout)
//   softmax: local max over 8 regs + shfl_xor(16,32); exp2; cvt_pk -> bf16 P
//   O^T += mfma(A=V^T-frag, B=P)  -- V^T slots chosen to match P's key order,
//   so correctness is independent of the HW A/B k-slot mapping (reduction
//   index permutation cancels; A and B use identical slot rules).
// Grid: 1024 blocks x 4 waves; block -> (bh, 4 consecutive q-tiles),
// largest q-tiles dispatched first for load balance.  No LDS, no barriers.
// ---------------------------------------------------------------------------
__global__ __launch_bounds__(256) void attn_fwd(
    const unsigned short* __restrict__ Qbf, const unsigned short* __restrict__ Kbf,
    const unsigned short* __restrict__ Vt, float* __restrict__ att) {
  const int tid = threadIdx.x;
  const int w = tid >> 6, l = tid & 63;
  const int g = l >> 4, col = l & 15;   // col: this lane's query (and V^T d-row)
  const int idx = blockIdx.x;
  const int qg = 63 - (idx >> 4);       // descending tile sizes
  const int bh = idx & 15;
  const int qt = qg * 4 + w;            // q-tile 0..255
  const int q0 = qt * 16;

  const unsigned short* Qp = Qbf + (size_t)bh * T * D;
  const unsigned short* Kp = Kbf + (size_t)bh * T * D;
  const unsigned short* Vp = Vt + (size_t)bh * D * T;

  // Q^T fragment (B operand), loaded once: lane g<2 holds Q[q0+col][8g..8g+7]
  bf16x8 qf = {0, 0, 0, 0, 0, 0, 0, 0};
  if (g < 2) qf = *(const bf16x8*)(Qp + ((size_t)(q0 + col)) * D + g * 8);

  float m = -1e30f, lsum = 0.f;
  f32x4 o = {0.f, 0.f, 0.f, 0.f};

  const int nb = (qt >> 1) + 1;         // 32-key blocks; last one masked
  for (int kb = 0; kb < nb; ++kb) {
    const int k0 = kb * 32;
    // K fragments (A operand): row = l&15 = key-within-16
    bf16x8 ka = {0, 0, 0, 0, 0, 0, 0, 0};
    bf16x8 kb2 = {0, 0, 0, 0, 0, 0, 0, 0};
    if (g < 2) {
      ka  = *(const bf16x8*)(Kp + ((size_t)(k0 + col)) * D + g * 8);
      kb2 = *(const bf16x8*)(Kp + ((size_t)(k0 + 16 + col)) * D + g * 8);
    }
    // V^T fragment: slots j=0..3 <- keys k0+4g..+3, j=4..7 <- keys k0+16+4g..+3
    union { bf16x8 v; u16x4 h[2]; } vf;
    vf.h[0] = *(const u16x4*)(Vp + (size_t)col * T + k0 + 4 * g);
    vf.h[1] = *(const u16x4*)(Vp + (size_t)col * T + k0 + 16 + 4 * g);

    f32x4 s0 = {0.f, 0.f, 0.f, 0.f};
    f32x4 s1 = {0.f, 0.f, 0.f, 0.f};
    s0 = __builtin_amdgcn_mfma_f32_16x16x32_bf16(ka, qf, s0, 0, 0, 0);
    s1 = __builtin_amdgcn_mfma_f32_16x16x32_bf16(kb2, qf, s1, 0, 0, 0);

    if (kb == nb - 1) {                 // causal mask on the diagonal block
      const int q = q0 + col;
      const int kA = k0 + 4 * g;
#pragma unroll
      for (int r = 0; r < 4; ++r) {
        if (kA + r > q) s0[r] = -1e30f;
        if (kA + 16 + r > q) s1[r] = -1e30f;
      }
    }

    float tm = fmaxf(fmaxf(fmaxf(s0[0], s0[1]), fmaxf(s0[2], s0[3])),
                     fmaxf(fmaxf(s1[0], s1[1]), fmaxf(s1[2], s1[3])));
    tm = fmaxf(tm, __shfl_xor(tm, 16, 64));
    tm = fmaxf(tm, __shfl_xor(tm, 32, 64));
    const float mn = fmaxf(m, tm);
    const float alpha = EXP2F(m - mn);
    m = mn;
    lsum *= alpha;
    o[0] *= alpha; o[1] *= alpha; o[2] *= alpha; o[3] *= alpha;

    float p0[4], p1[4];
#pragma unroll
    for (int r = 0; r < 4; ++r) {
      p0[r] = EXP2F(s0[r] - mn);
      p1[r] = EXP2F(s1[r] - mn);
    }
    lsum += (p0[0] + p0[1]) + (p0[2] + p0[3]) + (p1[0] + p1[1]) + (p1[2] + p1[3]);

    union { bf16x8 v; uint32_t u[4]; } pb;
    pb.u[0] = cvt_pk_bf16(p0[0], p0[1]);
    pb.u[1] = cvt_pk_bf16(p0[2], p0[3]);
    pb.u[2] = cvt_pk_bf16(p1[0], p1[1]);
    pb.u[3] = cvt_pk_bf16(p1[2], p1[3]);

    o = __builtin_amdgcn_mfma_f32_16x16x32_bf16(vf.v, pb.v, o, 0, 0, 0);
  }

  float Ltot = lsum;
  Ltot += __shfl_xor(Ltot, 16, 64);
  Ltot += __shfl_xor(Ltot, 32, 64);
  const float inv = 1.f / Ltot;
  // lane holds O^T[d=4g+r][q=col] -> att[bh][q0+col][4g..4g+3]
  *(float4*)(att + (((size_t)bh * T) + q0 + col) * D + 4 * g) =
      make_float4(o[0] * inv, o[1] * inv, o[2] * inv, o[3] * inv);
}

// ---------------------------------------------------------------------------
// Kernel 3: output projection + bias (fp32, unchanged).
// ---------------------------------------------------------------------------
__global__ __launch_bounds__(256) void out_proj(
    const float* __restrict__ att, const float* __restrict__ Wp,
    const float* __restrict__ bp, float* __restrict__ out) {
  __shared__ float As[128][68];
  __shared__ float Bs[128][68];
  const int tid = threadIdx.x;
  const int t0 = blockIdx.x * 64;
  const int c0 = blockIdx.y * 64;

  for (int f = tid; f < 2048; f += 256) {
    const int mm = f & 63;
    const int cp = (f >> 6) << 2;
    const int tr = t0 + mm;
    const int b = tr >> 12, t = tr & (T - 1);
    const int h = cp >> 4, d0 = cp & 15;
    const float4 v = *(const float4*)(att + (((size_t)b * H + h) * T + t) * D + d0);
    As[cp + 0][mm] = v.x; As[cp + 1][mm] = v.y; As[cp + 2][mm] = v.z; As[cp + 3][mm] = v.w;
  }
  const float4* wsrc = (const float4*)(Wp + (size_t)c0 * C);
  for (int f = tid; f < 2048; f += 256) {
    const float4 v = wsrc[f];
    const int n = f >> 5, k = (f & 31) << 2;
    Bs[k + 0][n] = v.x; Bs[k + 1][n] = v.y; Bs[k + 2][n] = v.z; Bs[k + 3][n] = v.w;
  }
  __syncthreads();

  const int tx = tid & 15, ty = tid >> 4;
  float acc[4][4] = {};
#pragma unroll 8
  for (int k = 0; k < 128; ++k) {
    const float4 a = *(const float4*)&As[k][ty * 4];
    const float4 b = *(const float4*)&Bs[k][tx * 4];
    const float av[4] = {a.x, a.y, a.z, a.w};
    const float bv[4] = {b.x, b.y, b.z, b.w};
#pragma unroll
    for (int i = 0; i < 4; ++i)
#pragma unroll
      for (int j = 0; j < 4; ++j) acc[i][j] = fmaf(av[i], bv[j], acc[i][j]);
  }

  const float4 bias = *(const float4*)(bp + c0 + tx * 4);
#pragma unroll
  for (int i = 0; i < 4; ++i) {
    const int tr = t0 + ty * 4 + i;
    const float4 v = make_float4(acc[i][0] + bias.x, acc[i][1] + bias.y,
                                 acc[i][2] + bias.z, acc[i][3] + bias.w);
    *(float4*)(out + (size_t)tr * C + c0 + tx * 4) = v;
  }
}

}  // namespace

extern "C" void kernel_launch(void* const* d_in, const int* in_sizes, int n_in,
                              void* d_out, int out_size, void* d_ws, size_t ws_size,
                              hipStream_t stream) {
  // setup_inputs order: x, Wk, Wq, Wv, Wp, bp
  const float* x  = (const float*)d_in[0];
  const float* Wk = (const float*)d_in[1];
  const float* Wq = (const float*)d_in[2];
  const float* Wv = (const float*)d_in[3];
  const float* Wp = (const float*)d_in[4];
  const float* bp = (const float*)d_in[5];

  float* att = (float*)d_ws;                        // 4 MiB fp32
  unsigned short* Qbf = (unsigned short*)(att + PLANE);  // 2 MiB bf16
  unsigned short* Kbf = Qbf + PLANE;                // 2 MiB
  unsigned short* Vtb = Kbf + PLANE;                // 2 MiB  (total 10 MiB ws)

  qkv_proj<<<dim3(128, 6), 256, 0, stream>>>(x, Wq, Wk, Wv, Qbf, Kbf, Vtb);
  attn_fwd<<<dim3(1024), 256, 0, stream>>>(Qbf, Kbf, Vtb, att);
  out_proj<<<dim3(128, 2), 256, 0, stream>>>(att, Wp, bp, (float*)d_out);
}

// Round 3
// 103.654 us; speedup vs baseline: 2.0205x; 1.2659x over previous
//
#include <hip/hip_runtime.h>

#ifndef __has_builtin
#define __has_builtin(x) 0
#endif
#if __has_builtin(__builtin_amdgcn_exp2f)
#define EXP2F(x) __builtin_amdgcn_exp2f(x)
#else
#define EXP2F(x) exp2f(x)
#endif

namespace {

constexpr int T = 4096;
constexpr int C = 128;
constexpr int H = 8;
constexpr int D = 16;
constexpr int BH = 16;                         // B*H
constexpr size_t PLANE = (size_t)BH * T * D;   // 1,048,576 elements per tensor

using bf16x8 = __attribute__((ext_vector_type(8))) short;
using u16x4  = __attribute__((ext_vector_type(4))) unsigned short;
using f32x16 = __attribute__((ext_vector_type(16))) float;

__device__ __forceinline__ uint32_t cvt_pk_bf16(float lo, float hi) {
  uint32_t r;
  asm volatile("v_cvt_pk_bf16_f32 %0, %1, %2" : "=v"(r) : "v"(lo), "v"(hi));
  return r;
}

// ---------------------------------------------------------------------------
// Kernel 1: QKV projection -> bf16, all global stores coalesced via LDS
// repack (round-2 epilogue wrote 8B/thread at 8KB strides -> ~30us tail).
//   Qbf[bh][t][d] (pre-scaled by D^-1/2*log2e), Kbf[bh][t][d], Vt[bh][d][t].
// ---------------------------------------------------------------------------
__global__ __launch_bounds__(256) void qkv_proj(
    const float* __restrict__ x, const float* __restrict__ Wq,
    const float* __restrict__ Wk, const float* __restrict__ Wv,
    unsigned short* __restrict__ Qbf, unsigned short* __restrict__ Kbf,
    unsigned short* __restrict__ Vt) {
  __shared__ float Xs[128][68];  // [k][m]
  __shared__ float Ws[128][68];  // [k][n]
  const int tid = threadIdx.x;
  const int bm = blockIdx.x;            // 128 row blocks
  const int bn = blockIdx.y;            // 6 col blocks
  const int mat = bn >> 1;              // 0=Q 1=K 2=V
  const int c0 = (bn & 1) * 64;
  const float* W = (mat == 0) ? Wq : (mat == 1) ? Wk : Wv;
  const int t0 = bm * 64;

  const float4* xsrc = (const float4*)(x + (size_t)t0 * C);
  const float4* wsrc = (const float4*)(W + (size_t)c0 * C);
  for (int f = tid; f < 2048; f += 256) {
    const int m = f >> 5, k = (f & 31) << 2;
    float4 v = xsrc[f];
    Xs[k + 0][m] = v.x; Xs[k + 1][m] = v.y; Xs[k + 2][m] = v.z; Xs[k + 3][m] = v.w;
    float4 u = wsrc[f];
    Ws[k + 0][m] = u.x; Ws[k + 1][m] = u.y; Ws[k + 2][m] = u.z; Ws[k + 3][m] = u.w;
  }
  __syncthreads();

  const int tx = tid & 15, ty = tid >> 4;
  float acc[4][4] = {};
#pragma unroll 8
  for (int k = 0; k < 128; ++k) {
    const float4 a = *(const float4*)&Xs[k][ty * 4];
    const float4 b = *(const float4*)&Ws[k][tx * 4];
    const float av[4] = {a.x, a.y, a.z, a.w};
    const float bv[4] = {b.x, b.y, b.z, b.w};
#pragma unroll
    for (int i = 0; i < 4; ++i)
#pragma unroll
      for (int j = 0; j < 4; ++j) acc[i][j] = fmaf(av[i], bv[j], acc[i][j]);
  }
  __syncthreads();  // done reading Xs -> reuse as bf16 staging

  unsigned short* Ls = (unsigned short*)&Xs[0][0];  // [64][72] bf16, 9216 B
  if (mat < 2) {
    const float sc = (mat == 0) ? 0.25f * 1.4426950408889634f : 1.0f;
#pragma unroll
    for (int i = 0; i < 4; ++i) {                 // Ls[t][c] packed bf16
      const uint32_t u0 = cvt_pk_bf16(acc[i][0] * sc, acc[i][1] * sc);
      const uint32_t u1 = cvt_pk_bf16(acc[i][2] * sc, acc[i][3] * sc);
      *(uint32_t*)&Ls[(ty * 4 + i) * 72 + tx * 4]     = u0;
      *(uint32_t*)&Ls[(ty * 4 + i) * 72 + tx * 4 + 2] = u1;
    }
    __syncthreads();
    unsigned short* dst = (mat == 0) ? Qbf : Kbf;
    const int lane = tid & 63, hp = tid >> 6;     // wave hp handles head-slot hp
    const int tr = t0 + lane, b = tr >> 12, t = tr & (T - 1);
    const int head = (c0 >> 4) + hp;
    unsigned short* base = dst + (((size_t)(b * H + head)) * T + t) * D;
#pragma unroll
    for (int p = 0; p < 2; ++p)                   // 2x16B per lane, coalesced
      *(uint4*)(base + p * 8) = *(const uint4*)&Ls[lane * 72 + hp * 16 + p * 8];
  } else {
#pragma unroll
    for (int j = 0; j < 4; ++j) {                 // Ls[c][t] (transposed)
      const uint32_t u0 = cvt_pk_bf16(acc[0][j], acc[1][j]);
      const uint32_t u1 = cvt_pk_bf16(acc[2][j], acc[3][j]);
      *(uint32_t*)&Ls[(tx * 4 + j) * 72 + ty * 4]     = u0;
      *(uint32_t*)&Ls[(tx * 4 + j) * 72 + ty * 4 + 2] = u1;
    }
    __syncthreads();
    const int c = tid >> 2;                       // 0..63
    const int b = t0 >> 12;
    const int head = (c0 + c) >> 4, dv = (c0 + c) & 15;
    unsigned short* base =
        Vt + (((size_t)(b * H + head)) * D + dv) * T + (t0 & (T - 1));
#pragma unroll
    for (int it = 0; it < 2; ++it) {              // 2x16B per lane along t
      const int part = (tid & 3) + 4 * it;
      *(uint4*)(base + part * 8) = *(const uint4*)&Ls[c * 72 + part * 8];
    }
  }
}

// ---------------------------------------------------------------------------
// Kernel 2: causal flash attention via 32x32x16 bf16 MFMA (K=16 = D, no pad).
// Block = (bh, 32-query tile), 4 waves = 4-way split-K over 32-key steps.
// Per step per wave:  S^T = mfma32(A=K, B=Q^T)  -- 1 MFMA, all lanes full.
//   lane l: query q=l&31, scores s16[r] for key k0+(r&3)+8*(r>>2)+4*(l>>5).
//   defer-max softmax: lane-local max + __all check; no shfl/rescale in the
//   common path (scores are tiny: 0.02-scaled weights).
//   O^T += mfma32(A=V^T, B=P) x2 -- P fed in-register; V^T slot placement
//   uses the identical (reg,half)->key function, so the unknown HW k-slot
//   mapping cancels (same trick validated in round 2).
// Split partials (m,l,o) merged through LDS once per block.
// ---------------------------------------------------------------------------
__global__ __launch_bounds__(256) void attn_fwd(
    const unsigned short* __restrict__ Qbf, const unsigned short* __restrict__ Kbf,
    const unsigned short* __restrict__ Vt, float* __restrict__ att) {
  __shared__ float Om[4][32];
  __shared__ float Ol[4][32];
  __shared__ float Oo[4][32][17];   // [split][q][d] padded
  const int tid = threadIdx.x;
  const int w = tid >> 6, l = tid & 63;
  const int lane31 = l & 31, h = l >> 5;
  const int idx = blockIdx.x;
  const int tile = 127 - (idx >> 4);   // big tiles dispatch first
  const int bh = idx & 15;
  const int q0 = tile * 32;
  const int ns = tile + 1;             // 32-key steps
  const int qidx = q0 + lane31;

  const unsigned short* Qp = Qbf + (size_t)bh * T * D;
  const unsigned short* Kp = Kbf + (size_t)bh * T * D;
  const unsigned short* Vp = Vt + (size_t)bh * D * T;
  const int dv = l & 15;               // clamped d-row for V loads

  const bf16x8 qf = *(const bf16x8*)(Qp + (size_t)qidx * D + 8 * h);

  f32x16 acc = {};
  float m = -1e30f, lsum = 0.f;

  int s = w;
  bf16x8 kf = {};
  u16x4 v0 = {}, v1 = {}, v2 = {}, v3 = {};
  if (s < ns) {
    const int k0 = s * 32;
    kf = *(const bf16x8*)(Kp + (size_t)(k0 + lane31) * D + 8 * h);
    const unsigned short* vb = Vp + (size_t)dv * T + k0 + 4 * h;
    v0 = *(const u16x4*)(vb);      v1 = *(const u16x4*)(vb + 8);
    v2 = *(const u16x4*)(vb + 16); v3 = *(const u16x4*)(vb + 24);
  }

  while (s < ns) {
    // prefetch next step's fragments (hide L2 latency under softmax)
    bf16x8 kfn = {};
    u16x4 n0 = {}, n1 = {}, n2 = {}, n3 = {};
    if (s + 4 < ns) {
      const int k1 = (s + 4) * 32;
      kfn = *(const bf16x8*)(Kp + (size_t)(k1 + lane31) * D + 8 * h);
      const unsigned short* vb = Vp + (size_t)dv * T + k1 + 4 * h;
      n0 = *(const u16x4*)(vb);      n1 = *(const u16x4*)(vb + 8);
      n2 = *(const u16x4*)(vb + 16); n3 = *(const u16x4*)(vb + 24);
    }

    const int k0 = s * 32;
    f32x16 s16 = {};
    s16 = __builtin_amdgcn_mfma_f32_32x32x16_bf16(kf, qf, s16, 0, 0, 0);

    if (s == tile) {                    // causal mask, diagonal step only
#pragma unroll
      for (int r = 0; r < 16; ++r) {
        const int key = k0 + (r & 3) + 8 * (r >> 2) + 4 * h;
        if (key > qidx) s16[r] = -1e30f;
      }
    }

    float lm = fmaxf(s16[0], s16[1]);
#pragma unroll
    for (int r = 2; r < 16; ++r) lm = fmaxf(lm, s16[r]);

    if (s == w) {                       // first step: establish m
      m = fmaxf(lm, __shfl_xor(lm, 32, 64));
    } else if (!__all(lm <= m + 8.f)) { // rare rescale path
      const float tm = fmaxf(lm, __shfl_xor(lm, 32, 64));
      const float mn = fmaxf(m, tm);
      const float alpha = EXP2F(m - mn);
      lsum *= alpha;
#pragma unroll
      for (int j = 0; j < 8; ++j) acc[j] *= alpha;
      m = mn;
    }

#pragma unroll
    for (int r = 0; r < 16; ++r) s16[r] = EXP2F(s16[r] - m);
    lsum += ((s16[0] + s16[1]) + (s16[2] + s16[3])) +
            ((s16[4] + s16[5]) + (s16[6] + s16[7])) +
            ((s16[8] + s16[9]) + (s16[10] + s16[11])) +
            ((s16[12] + s16[13]) + (s16[14] + s16[15]));

    union PF { bf16x8 v; uint32_t u[4]; } pa, pb;
    pa.u[0] = cvt_pk_bf16(s16[0], s16[1]);
    pa.u[1] = cvt_pk_bf16(s16[2], s16[3]);
    pa.u[2] = cvt_pk_bf16(s16[4], s16[5]);
    pa.u[3] = cvt_pk_bf16(s16[6], s16[7]);
    pb.u[0] = cvt_pk_bf16(s16[8], s16[9]);
    pb.u[1] = cvt_pk_bf16(s16[10], s16[11]);
    pb.u[2] = cvt_pk_bf16(s16[12], s16[13]);
    pb.u[3] = cvt_pk_bf16(s16[14], s16[15]);

    union VF { bf16x8 v; u16x4 q4[2]; } va, vb2;
    va.q4[0] = v0;  va.q4[1] = v1;     // keys k0+0..15  (slot fn = P's)
    vb2.q4[0] = v2; vb2.q4[1] = v3;    // keys k0+16..31
    acc = __builtin_amdgcn_mfma_f32_32x32x16_bf16(va.v, pa.v, acc, 0, 0, 0);
    acc = __builtin_amdgcn_mfma_f32_32x32x16_bf16(vb2.v, pb.v, acc, 0, 0, 0);

    kf = kfn; v0 = n0; v1 = n1; v2 = n2; v3 = n3;
    s += 4;
  }

  lsum += __shfl_xor(lsum, 32, 64);     // combine lane pair (same q)

  Om[w][lane31] = m;                    // both halves write identical value
  Ol[w][lane31] = lsum;
#pragma unroll
  for (int j = 0; j < 8; ++j) {
    const int dj = (j & 3) + 8 * (j >> 2) + 4 * h;
    Oo[w][lane31][dj] = acc[j];
  }
  __syncthreads();

  if (w == 0) {
    float M = Om[0][lane31];
#pragma unroll
    for (int p = 1; p < 4; ++p) M = fmaxf(M, Om[p][lane31]);
    float L = 0.f, od[8] = {};
#pragma unroll
    for (int p = 0; p < 4; ++p) {
      const float wsc = EXP2F(Om[p][lane31] - M);
      L = fmaf(Ol[p][lane31], wsc, L);
#pragma unroll
      for (int j = 0; j < 8; ++j) {
        const int dj = (j & 3) + 8 * (j >> 2) + 4 * h;
        od[j] = fmaf(Oo[p][lane31][dj], wsc, od[j]);
      }
    }
    const float inv = 1.f / L;
    float* base = att + ((size_t)bh * T + qidx) * D;
    *(float4*)(base + 4 * h) =
        make_float4(od[0] * inv, od[1] * inv, od[2] * inv, od[3] * inv);
    *(float4*)(base + 8 + 4 * h) =
        make_float4(od[4] * inv, od[5] * inv, od[6] * inv, od[7] * inv);
  }
}

// ---------------------------------------------------------------------------
// Kernel 3: output projection + bias (fp32, unchanged).
// ---------------------------------------------------------------------------
__global__ __launch_bounds__(256) void out_proj(
    const float* __restrict__ att, const float* __restrict__ Wp,
    const float* __restrict__ bp, float* __restrict__ out) {
  __shared__ float As[128][68];
  __shared__ float Bs[128][68];
  const int tid = threadIdx.x;
  const int t0 = blockIdx.x * 64;
  const int c0 = blockIdx.y * 64;

  for (int f = tid; f < 2048; f += 256) {
    const int mm = f & 63;
    const int cp = (f >> 6) << 2;
    const int tr = t0 + mm;
    const int b = tr >> 12, t = tr & (T - 1);
    const int h = cp >> 4, d0 = cp & 15;
    const float4 v = *(const float4*)(att + (((size_t)b * H + h) * T + t) * D + d0);
    As[cp + 0][mm] = v.x; As[cp + 1][mm] = v.y; As[cp + 2][mm] = v.z; As[cp + 3][mm] = v.w;
  }
  const float4* wsrc = (const float4*)(Wp + (size_t)c0 * C);
  for (int f = tid; f < 2048; f += 256) {
    const float4 v = wsrc[f];
    const int n = f >> 5, k = (f & 31) << 2;
    Bs[k + 0][n] = v.x; Bs[k + 1][n] = v.y; Bs[k + 2][n] = v.z; Bs[k + 3][n] = v.w;
  }
  __syncthreads();

  const int tx = tid & 15, ty = tid >> 4;
  float acc[4][4] = {};
#pragma unroll 8
  for (int k = 0; k < 128; ++k) {
    const float4 a = *(const float4*)&As[k][ty * 4];
    const float4 b = *(const float4*)&Bs[k][tx * 4];
    const float av[4] = {a.x, a.y, a.z, a.w};
    const float bv[4] = {b.x, b.y, b.z, b.w};
#pragma unroll
    for (int i = 0; i < 4; ++i)
#pragma unroll
      for (int j = 0; j < 4; ++j) acc[i][j] = fmaf(av[i], bv[j], acc[i][j]);
  }

  const float4 bias = *(const float4*)(bp + c0 + tx * 4);
#pragma unroll
  for (int i = 0; i < 4; ++i) {
    const int tr = t0 + ty * 4 + i;
    const float4 v = make_float4(acc[i][0] + bias.x, acc[i][1] + bias.y,
                                 acc[i][2] + bias.z, acc[i][3] + bias.w);
    *(float4*)(out + (size_t)tr * C + c0 + tx * 4) = v;
  }
}

}  // namespace

extern "C" void kernel_launch(void* const* d_in, const int* in_sizes, int n_in,
                              void* d_out, int out_size, void* d_ws, size_t ws_size,
                              hipStream_t stream) {
  // setup_inputs order: x, Wk, Wq, Wv, Wp, bp
  const float* x  = (const float*)d_in[0];
  const float* Wk = (const float*)d_in[1];
  const float* Wq = (const float*)d_in[2];
  const float* Wv = (const float*)d_in[3];
  const float* Wp = (const float*)d_in[4];
  const float* bp = (const float*)d_in[5];

  float* att = (float*)d_ws;                             // 4 MiB fp32
  unsigned short* Qbf = (unsigned short*)(att + PLANE);  // 2 MiB bf16
  unsigned short* Kbf = Qbf + PLANE;                     // 2 MiB
  unsigned short* Vtb = Kbf + PLANE;                     // 2 MiB (10 MiB ws)

  qkv_proj<<<dim3(128, 6), 256, 0, stream>>>(x, Wq, Wk, Wv, Qbf, Kbf, Vtb);
  attn_fwd<<<dim3(2048), 256, 0, stream>>>(Qbf, Kbf, Vtb, att);
  out_proj<<<dim3(128, 2), 256, 0, stream>>>(att, Wp, bp, (float*)d_out);
}